// Round 2
// baseline (485.170 us; speedup 1.0000x reference)
//
#include <hip/hip_runtime.h>
#include <hip/hip_bf16.h>

typedef __bf16 bf16x8 __attribute__((ext_vector_type(8)));
typedef float f32x4 __attribute__((ext_vector_type(4)));
typedef unsigned int u32;
typedef unsigned short u16;
typedef u32 u32x4 __attribute__((ext_vector_type(4)));
typedef u16 u16x4 __attribute__((ext_vector_type(4)));

// round-to-nearest-even f32 -> bf16
__device__ __forceinline__ u16 f2bf(float x) {
  u32 u = __float_as_uint(x);
  return (u16)((u + 0x7FFFu + ((u >> 16) & 1u)) >> 16);
}

__device__ __forceinline__ bf16x8 ld_frag_lds(const u16* base, int byteOff) {
  u32x4 v = *(const u32x4*)((const char*)base + byteOff);
  return __builtin_bit_cast(bf16x8, v);
}

__device__ __forceinline__ bf16x8 ld_frag_glb(const u16* p) {
  u32x4 v = *(const u32x4*)p;
  return __builtin_bit_cast(bf16x8, v);
}

// ---------------------------------------------------------------------------
// Prep: convert W2a [256x256] f32 and W2b [256x64] f32 into bf16 fragments
// laid out in the exact per-lane order GEMM loads them:
//   wfA[((ntg*8 + ks)*64 + lane)*8 + q] = W2a[ks*32 + (lane>>4)*8 + q][ntg*16 + (lane&15)]
// ---------------------------------------------------------------------------
__global__ void prep_kernel(const float* __restrict__ W2a, const float* __restrict__ W2b,
                            u16* __restrict__ wfA, u16* __restrict__ wfB) {
  int t = blockIdx.x * 256 + threadIdx.x;
  if (t < 8192) {  // 16 ntiles * 8 ksteps * 64 lanes
    int lane = t & 63;
    int ks = (t >> 6) & 7;
    int ntg = t >> 9;  // 0..15
    int col = (ntg << 4) + (lane & 15);
    int kb = (ks << 5) + ((lane >> 4) << 3);
#pragma unroll
    for (int q = 0; q < 8; ++q)
      wfA[t * 8 + q] = f2bf(W2a[(kb + q) * 256 + col]);
  } else if (t < 10240) {  // 4 ntiles * 8 ksteps * 64 lanes
    int t2 = t - 8192;
    int lane = t2 & 63;
    int ks = (t2 >> 6) & 7;
    int ntg = t2 >> 9;  // 0..3
    int col = (ntg << 4) + (lane & 15);
    int kb = (ks << 5) + ((lane >> 4) << 3);
#pragma unroll
    for (int q = 0; q < 8; ++q)
      wfB[t2 * 8 + q] = f2bf(W2b[(kb + q) * 64 + col]);
  }
}

// ---------------------------------------------------------------------------
// Fused kernel. Blocks [0,8192): out2 path. Blocks [8192,10240): out1 path.
// out2 blocks are dispatched first (they're the long pole); out1's
// memory-bound blocks fill the tail.
//
// out2: one block = (b, i, j-tile of 64). Fused MLP with bf16 MFMA.
// X row r (j = j0+r) = [emb1[b,j] | emb2[b,j,i] | emb1[b,i] | emb2[b,i,j]] (256)
// Single 32 KB LDS buffer S: holds X during GEMM1, reused for H in GEMM2
// (extra __syncthreads between GEMM1 reads and H writes).
// XOR swizzle: byte ^= (row&7)<<4 (rows are 512B).
// ---------------------------------------------------------------------------
__global__ __launch_bounds__(256, 5) void fused_kernel(
    const float* __restrict__ emb1, const float* __restrict__ emb2,
    const float* __restrict__ W1a, const float* __restrict__ b1a,
    const float* __restrict__ W1b, const float* __restrict__ b1b,
    const float* __restrict__ b2a, const float* __restrict__ b2b,
    const u16* __restrict__ wfA, const u16* __restrict__ wfB,
    float* __restrict__ out1, float* __restrict__ out2) {
  __shared__ __align__(16) u16 S[64 * 256];  // 32 KB

  int blk = blockIdx.x;
  int t = threadIdx.x;

  if (blk >= 8192) {
    // ---------------- out1 path ----------------
    int bi = blk - 8192;  // b*256 + i
    float* f = (float*)S;
    float* smax = f;        // [4][64]
    float* smin = f + 256;  // [4][64]
    float* cat1 = f + 512;  // [192]
    float* h    = f + 704;  // [128]

    int d = t & 63, q = t >> 6;
    const float* base = emb2 + (size_t)bi * 256 * 64;
    float vmax = -INFINITY, vmin = INFINITY;
    for (int j = q; j < 256; j += 4) {
      float v = base[j * 64 + d];
      vmax = fmaxf(vmax, v);
      vmin = fminf(vmin, v);
    }
    smax[q * 64 + d] = vmax;
    smin[q * 64 + d] = vmin;
    __syncthreads();
    if (t < 64) {
      float mx = fmaxf(fmaxf(smax[t], smax[64 + t]), fmaxf(smax[128 + t], smax[192 + t]));
      float mn = fminf(fminf(smin[t], smin[64 + t]), fminf(smin[128 + t], smin[192 + t]));
      cat1[t] = emb1[bi * 64 + t];
      cat1[64 + t] = mx;
      cat1[128 + t] = mn;
    }
    __syncthreads();
    if (t < 128) {
      float acc = b1a[t];
      for (int k = 0; k < 192; ++k) acc += cat1[k] * W1a[k * 128 + t];
      h[t] = fmaxf(acc, 0.f);
    }
    __syncthreads();
    if (t < 64) {
      float acc = b1b[t];
      for (int k = 0; k < 128; ++k) acc += h[k] * W1b[k * 64 + t];
      out1[bi * 64 + t] = acc;
    }
    return;
  }

  // ---------------- out2 path ----------------
  int b = blk >> 10;
  int i = (blk >> 2) & 255;
  int j0 = (blk & 3) << 6;
  int lane = t & 63;
  int w = t >> 6;
  int lr = lane & 15;  // row/col within 16-tile
  int lg = lane >> 4;  // k-group

  // ---- stage X: 64 rows x 256 feats -> bf16 LDS (swizzled) ----
  {
    int r = t >> 2;
    int c0 = (t & 3) << 4;
    const float* s0 = emb1 + ((b << 8) + j0 + r) * 64;
    const float* s1 = emb2 + ((((size_t)(b << 8) + j0 + r) << 8) + i) * 64;
    const float* s2 = emb1 + ((b << 8) + i) * 64;
    const float* s3 = emb2 + ((((size_t)(b << 8) + i) << 8) + (j0 + r)) * 64;
    const float* srcs[4] = {s0, s1, s2, s3};
#pragma unroll
    for (int seg = 0; seg < 4; ++seg) {
      const float* src = srcs[seg];
#pragma unroll
      for (int u = 0; u < 4; ++u) {
        int d = c0 + (u << 2);
        float4 v = *(const float4*)(src + d);
        u16x4 o = {f2bf(v.x), f2bf(v.y), f2bf(v.z), f2bf(v.w)};
        int byteOff = (r * 512 + ((seg << 6) + d) * 2) ^ ((r & 7) << 4);
        *(u16x4*)((char*)S + byteOff) = o;
      }
    }
  }
  __syncthreads();

  // ---- GEMM1: H(64x256) = relu(X @ W2a + b2a); wave w owns cols [w*64, w*64+64) ----
  f32x4 acc1[4][4];
#pragma unroll
  for (int m = 0; m < 4; ++m)
#pragma unroll
    for (int nt = 0; nt < 4; ++nt) acc1[m][nt] = (f32x4){0.f, 0.f, 0.f, 0.f};

#pragma unroll
  for (int ks = 0; ks < 8; ++ks) {
    int kByte = (ks << 6) + (lg << 4);  // (ks*32 + lg*8) bf16 -> bytes
    bf16x8 a[4];
#pragma unroll
    for (int m = 0; m < 4; ++m) {
      int r = (m << 4) + lr;
      int off = (r * 512 + kByte) ^ ((r & 7) << 4);
      a[m] = ld_frag_lds(S, off);
    }
    bf16x8 bw[4];
#pragma unroll
    for (int nt = 0; nt < 4; ++nt)
      bw[nt] = ld_frag_glb(wfA + (size_t)((((w << 2) + nt) * 8 + ks) * 64 + lane) * 8);
#pragma unroll
    for (int m = 0; m < 4; ++m)
#pragma unroll
      for (int nt = 0; nt < 4; ++nt)
        acc1[m][nt] = __builtin_amdgcn_mfma_f32_16x16x32_bf16(a[m], bw[nt], acc1[m][nt], 0, 0, 0);
  }

  __syncthreads();  // all waves done READING X before S is overwritten with H

  // ---- bias + relu -> S as H (bf16, swizzled). C/D map: col=lane&15, row=4*(lane>>4)+e ----
#pragma unroll
  for (int nt = 0; nt < 4; ++nt) {
    int n = (w << 6) + (nt << 4) + lr;
    float bias = b2a[n];
#pragma unroll
    for (int m = 0; m < 4; ++m) {
      int r0 = (m << 4) + (lg << 2);
#pragma unroll
      for (int e = 0; e < 4; ++e) {
        int r = r0 + e;
        float hv = fmaxf(acc1[m][nt][e] + bias, 0.f);
        int off = (r * 512 + n * 2) ^ ((r & 7) << 4);
        *(u16*)((char*)S + off) = f2bf(hv);
      }
    }
  }
  __syncthreads();

  // ---- GEMM2: out(64x64) = H @ W2b + b2b; wave w owns cols [w*16, w*16+16) ----
  f32x4 acc2[4];
#pragma unroll
  for (int m = 0; m < 4; ++m) acc2[m] = (f32x4){0.f, 0.f, 0.f, 0.f};

#pragma unroll
  for (int ks = 0; ks < 8; ++ks) {
    int kByte = (ks << 6) + (lg << 4);
    bf16x8 bw = ld_frag_glb(wfB + (size_t)(((w << 3) + ks) * 64 + lane) * 8);
#pragma unroll
    for (int m = 0; m < 4; ++m) {
      int r = (m << 4) + lr;
      int off = (r * 512 + kByte) ^ ((r & 7) << 4);
      bf16x8 a = ld_frag_lds(S, off);
      acc2[m] = __builtin_amdgcn_mfma_f32_16x16x32_bf16(a, bw, acc2[m], 0, 0, 0);
    }
  }

  // ---- store out2 tile (f32) ----
  int col = (w << 4) + lr;
  float bias2 = b2b[col];
  float* obase = out2 + ((((size_t)(b << 8) + i) << 8) + j0) * 64;
#pragma unroll
  for (int m = 0; m < 4; ++m) {
    int r0 = (m << 4) + (lg << 2);
#pragma unroll
    for (int e = 0; e < 4; ++e)
      obase[(size_t)(r0 + e) * 64 + col] = acc2[m][e] + bias2;
  }
}

extern "C" void kernel_launch(void* const* d_in, const int* in_sizes, int n_in,
                              void* d_out, int out_size, void* d_ws, size_t ws_size,
                              hipStream_t stream) {
  const float* emb1 = (const float*)d_in[0];
  const float* emb2 = (const float*)d_in[1];
  const float* W1a  = (const float*)d_in[2];
  const float* b1a  = (const float*)d_in[3];
  const float* W1b  = (const float*)d_in[4];
  const float* b1b  = (const float*)d_in[5];
  const float* W2a  = (const float*)d_in[6];
  const float* b2a  = (const float*)d_in[7];
  const float* W2b  = (const float*)d_in[8];
  const float* b2b  = (const float*)d_in[9];

  float* out = (float*)d_out;
  u16* wfA = (u16*)d_ws;               // 16*8*64*8 = 65536 bf16 = 128 KB
  u16* wfB = wfA + 16 * 8 * 64 * 8;    //  4*8*64*8 = 16384 bf16 =  32 KB

  prep_kernel<<<40, 256, 0, stream>>>(W2a, W2b, wfA, wfB);
  fused_kernel<<<10240, 256, 0, stream>>>(emb1, emb2, W1a, b1a, W1b, b1b,
                                          b2a, b2b, wfA, wfB,
                                          out, out + 8 * 256 * 64);
}

// Round 3
// 222.059 us; speedup vs baseline: 2.1849x; 2.1849x over previous
//
#include <hip/hip_runtime.h>
#include <hip/hip_bf16.h>

typedef __bf16 bf16x8 __attribute__((ext_vector_type(8)));
typedef float f32x4 __attribute__((ext_vector_type(4)));
typedef unsigned int u32;
typedef unsigned short u16;
typedef u32 u32x4 __attribute__((ext_vector_type(4)));
typedef u16 u16x4 __attribute__((ext_vector_type(4)));

// round-to-nearest-even f32 -> bf16
__device__ __forceinline__ u16 f2bf(float x) {
  u32 u = __float_as_uint(x);
  return (u16)((u + 0x7FFFu + ((u >> 16) & 1u)) >> 16);
}

__device__ __forceinline__ bf16x8 ld_frag_lds(const u16* base, int byteOff) {
  u32x4 v = *(const u32x4*)((const char*)base + byteOff);
  return __builtin_bit_cast(bf16x8, v);
}

__device__ __forceinline__ bf16x8 ld_frag_glb(const u16* p) {
  u32x4 v = *(const u32x4*)p;
  return __builtin_bit_cast(bf16x8, v);
}

// ---------------------------------------------------------------------------
// Prep: convert W2a [256x256] f32 and W2b [256x64] f32 into bf16 fragments
// laid out in the exact per-lane order GEMM loads them:
//   wfA[((ntg*8 + ks)*64 + lane)*8 + q] = W2a[ks*32 + (lane>>4)*8 + q][ntg*16 + (lane&15)]
// ---------------------------------------------------------------------------
__global__ void prep_kernel(const float* __restrict__ W2a, const float* __restrict__ W2b,
                            u16* __restrict__ wfA, u16* __restrict__ wfB) {
  int t = blockIdx.x * 256 + threadIdx.x;
  if (t < 8192) {  // 16 ntiles * 8 ksteps * 64 lanes
    int lane = t & 63;
    int ks = (t >> 6) & 7;
    int ntg = t >> 9;  // 0..15
    int col = (ntg << 4) + (lane & 15);
    int kb = (ks << 5) + ((lane >> 4) << 3);
#pragma unroll
    for (int q = 0; q < 8; ++q)
      wfA[t * 8 + q] = f2bf(W2a[(kb + q) * 256 + col]);
  } else if (t < 10240) {  // 4 ntiles * 8 ksteps * 64 lanes
    int t2 = t - 8192;
    int lane = t2 & 63;
    int ks = (t2 >> 6) & 7;
    int ntg = t2 >> 9;  // 0..3
    int col = (ntg << 4) + (lane & 15);
    int kb = (ks << 5) + ((lane >> 4) << 3);
#pragma unroll
    for (int q = 0; q < 8; ++q)
      wfB[t2 * 8 + q] = f2bf(W2b[(kb + q) * 64 + col]);
  }
}

// ---------------------------------------------------------------------------
// Fused kernel. Blocks [0,8192): out2 path. Blocks [8192,10240): out1 path.
// out2 blocks are dispatched first (they're the long pole); out1's
// memory-bound blocks fill the tail.
//
// out2: one block = (b, i, j-tile of 64). Fused MLP with bf16 MFMA.
// X row r (j = j0+r) = [emb1[b,j] | emb2[b,j,i] | emb1[b,i] | emb2[b,i,j]] (256)
// Single 32 KB LDS buffer S: holds X during GEMM1, reused for H in GEMM2
// (extra __syncthreads between GEMM1 reads and H writes).
// XOR swizzle: byte ^= (row&7)<<4 (rows are 512B).
//
// __launch_bounds__(256,4): VGPR cap 128 — kernel needs ~88-100; (256,5)
// capped at ~102 and the compiler SPILLED acc1 (R2: VGPR=48, FETCH +240MB,
// 4x regression). 4 blocks/CU via VGPR, LDS allows 5.
// ---------------------------------------------------------------------------
__global__ __launch_bounds__(256, 4) void fused_kernel(
    const float* __restrict__ emb1, const float* __restrict__ emb2,
    const float* __restrict__ W1a, const float* __restrict__ b1a,
    const float* __restrict__ W1b, const float* __restrict__ b1b,
    const float* __restrict__ b2a, const float* __restrict__ b2b,
    const u16* __restrict__ wfA, const u16* __restrict__ wfB,
    float* __restrict__ out1, float* __restrict__ out2) {
  __shared__ __align__(16) u16 S[64 * 256];  // 32 KB

  int blk = blockIdx.x;
  int t = threadIdx.x;

  if (blk >= 8192) {
    // ---------------- out1 path ----------------
    int bi = blk - 8192;  // b*256 + i
    float* f = (float*)S;
    float* smax = f;        // [4][64]
    float* smin = f + 256;  // [4][64]
    float* cat1 = f + 512;  // [192]
    float* h    = f + 704;  // [128]

    int d = t & 63, q = t >> 6;
    const float* base = emb2 + (size_t)bi * 256 * 64;
    float vmax = -INFINITY, vmin = INFINITY;
    for (int j = q; j < 256; j += 4) {
      float v = base[j * 64 + d];
      vmax = fmaxf(vmax, v);
      vmin = fminf(vmin, v);
    }
    smax[q * 64 + d] = vmax;
    smin[q * 64 + d] = vmin;
    __syncthreads();
    if (t < 64) {
      float mx = fmaxf(fmaxf(smax[t], smax[64 + t]), fmaxf(smax[128 + t], smax[192 + t]));
      float mn = fminf(fminf(smin[t], smin[64 + t]), fminf(smin[128 + t], smin[192 + t]));
      cat1[t] = emb1[bi * 64 + t];
      cat1[64 + t] = mx;
      cat1[128 + t] = mn;
    }
    __syncthreads();
    if (t < 128) {
      float acc = b1a[t];
      for (int k = 0; k < 192; ++k) acc += cat1[k] * W1a[k * 128 + t];
      h[t] = fmaxf(acc, 0.f);
    }
    __syncthreads();
    if (t < 64) {
      float acc = b1b[t];
      for (int k = 0; k < 128; ++k) acc += h[k] * W1b[k * 64 + t];
      out1[bi * 64 + t] = acc;
    }
    return;
  }

  // ---------------- out2 path ----------------
  int b = blk >> 10;
  int i = (blk >> 2) & 255;
  int j0 = (blk & 3) << 6;
  int lane = t & 63;
  int w = t >> 6;
  int lr = lane & 15;  // row/col within 16-tile
  int lg = lane >> 4;  // k-group

  // ---- stage X: 64 rows x 256 feats -> bf16 LDS (swizzled) ----
  {
    int r = t >> 2;
    int c0 = (t & 3) << 4;
    const float* s0 = emb1 + ((b << 8) + j0 + r) * 64;
    const float* s1 = emb2 + ((((size_t)(b << 8) + j0 + r) << 8) + i) * 64;
    const float* s2 = emb1 + ((b << 8) + i) * 64;
    const float* s3 = emb2 + ((((size_t)(b << 8) + i) << 8) + (j0 + r)) * 64;
    const float* srcs[4] = {s0, s1, s2, s3};
#pragma unroll
    for (int seg = 0; seg < 4; ++seg) {
      const float* src = srcs[seg];
#pragma unroll
      for (int u = 0; u < 4; ++u) {
        int d = c0 + (u << 2);
        float4 v = *(const float4*)(src + d);
        u16x4 o = {f2bf(v.x), f2bf(v.y), f2bf(v.z), f2bf(v.w)};
        int byteOff = (r * 512 + ((seg << 6) + d) * 2) ^ ((r & 7) << 4);
        *(u16x4*)((char*)S + byteOff) = o;
      }
    }
  }
  __syncthreads();

  // ---- GEMM1: H(64x256) = relu(X @ W2a + b2a); wave w owns cols [w*64, w*64+64) ----
  f32x4 acc1[4][4];
#pragma unroll
  for (int m = 0; m < 4; ++m)
#pragma unroll
    for (int nt = 0; nt < 4; ++nt) acc1[m][nt] = (f32x4){0.f, 0.f, 0.f, 0.f};

#pragma unroll
  for (int ks = 0; ks < 8; ++ks) {
    int kByte = (ks << 6) + (lg << 4);  // (ks*32 + lg*8) bf16 -> bytes
    bf16x8 a[4];
#pragma unroll
    for (int m = 0; m < 4; ++m) {
      int r = (m << 4) + lr;
      int off = (r * 512 + kByte) ^ ((r & 7) << 4);
      a[m] = ld_frag_lds(S, off);
    }
    bf16x8 bw[4];
#pragma unroll
    for (int nt = 0; nt < 4; ++nt)
      bw[nt] = ld_frag_glb(wfA + (size_t)((((w << 2) + nt) * 8 + ks) * 64 + lane) * 8);
#pragma unroll
    for (int m = 0; m < 4; ++m)
#pragma unroll
      for (int nt = 0; nt < 4; ++nt)
        acc1[m][nt] = __builtin_amdgcn_mfma_f32_16x16x32_bf16(a[m], bw[nt], acc1[m][nt], 0, 0, 0);
  }

  __syncthreads();  // all waves done READING X before S is overwritten with H

  // ---- bias + relu -> S as H (bf16, swizzled). C/D map: col=lane&15, row=4*(lane>>4)+e ----
#pragma unroll
  for (int nt = 0; nt < 4; ++nt) {
    int n = (w << 6) + (nt << 4) + lr;
    float bias = b2a[n];
#pragma unroll
    for (int m = 0; m < 4; ++m) {
      int r0 = (m << 4) + (lg << 2);
#pragma unroll
      for (int e = 0; e < 4; ++e) {
        int r = r0 + e;
        float hv = fmaxf(acc1[m][nt][e] + bias, 0.f);
        int off = (r * 512 + n * 2) ^ ((r & 7) << 4);
        *(u16*)((char*)S + off) = f2bf(hv);
      }
    }
  }
  __syncthreads();

  // ---- GEMM2: out(64x64) = H @ W2b + b2b; wave w owns cols [w*16, w*16+16) ----
  f32x4 acc2[4];
#pragma unroll
  for (int m = 0; m < 4; ++m) acc2[m] = (f32x4){0.f, 0.f, 0.f, 0.f};

#pragma unroll
  for (int ks = 0; ks < 8; ++ks) {
    int kByte = (ks << 6) + (lg << 4);
    bf16x8 bw = ld_frag_glb(wfB + (size_t)(((w << 3) + ks) * 64 + lane) * 8);
#pragma unroll
    for (int m = 0; m < 4; ++m) {
      int r = (m << 4) + lr;
      int off = (r * 512 + kByte) ^ ((r & 7) << 4);
      bf16x8 a = ld_frag_lds(S, off);
      acc2[m] = __builtin_amdgcn_mfma_f32_16x16x32_bf16(a, bw, acc2[m], 0, 0, 0);
    }
  }

  // ---- store out2 tile (f32) ----
  int col = (w << 4) + lr;
  float bias2 = b2b[col];
  float* obase = out2 + ((((size_t)(b << 8) + i) << 8) + j0) * 64;
#pragma unroll
  for (int m = 0; m < 4; ++m) {
    int r0 = (m << 4) + (lg << 2);
#pragma unroll
    for (int e = 0; e < 4; ++e)
      obase[(size_t)(r0 + e) * 64 + col] = acc2[m][e] + bias2;
  }
}

extern "C" void kernel_launch(void* const* d_in, const int* in_sizes, int n_in,
                              void* d_out, int out_size, void* d_ws, size_t ws_size,
                              hipStream_t stream) {
  const float* emb1 = (const float*)d_in[0];
  const float* emb2 = (const float*)d_in[1];
  const float* W1a  = (const float*)d_in[2];
  const float* b1a  = (const float*)d_in[3];
  const float* W1b  = (const float*)d_in[4];
  const float* b1b  = (const float*)d_in[5];
  const float* W2a  = (const float*)d_in[6];
  const float* b2a  = (const float*)d_in[7];
  const float* W2b  = (const float*)d_in[8];
  const float* b2b  = (const float*)d_in[9];

  float* out = (float*)d_out;
  u16* wfA = (u16*)d_ws;               // 16*8*64*8 = 65536 bf16 = 128 KB
  u16* wfB = wfA + 16 * 8 * 64 * 8;    //  4*8*64*8 = 16384 bf16 =  32 KB

  prep_kernel<<<40, 256, 0, stream>>>(W2a, W2b, wfA, wfB);
  fused_kernel<<<10240, 256, 0, stream>>>(emb1, emb2, W1a, b1a, W1b, b1b,
                                          b2a, b2b, wfA, wfB,
                                          out, out + 8 * 256 * 64);
}

// Round 4
// 187.015 us; speedup vs baseline: 2.5943x; 1.1874x over previous
//
#include <hip/hip_runtime.h>
#include <hip/hip_bf16.h>

typedef __bf16 bf16x8 __attribute__((ext_vector_type(8)));
typedef float f32x4 __attribute__((ext_vector_type(4)));
typedef unsigned int u32;
typedef unsigned short u16;
typedef u32 u32x4 __attribute__((ext_vector_type(4)));
typedef u16 u16x4 __attribute__((ext_vector_type(4)));
typedef u16 u16x8 __attribute__((ext_vector_type(8)));

// round-to-nearest-even f32 -> bf16
__device__ __forceinline__ u16 f2bf(float x) {
  u32 u = __float_as_uint(x);
  return (u16)((u + 0x7FFFu + ((u >> 16) & 1u)) >> 16);
}

__device__ __forceinline__ bf16x8 ld_frag_lds(const u16* base, int byteOff) {
  u32x4 v = *(const u32x4*)((const char*)base + byteOff);
  return __builtin_bit_cast(bf16x8, v);
}

__device__ __forceinline__ bf16x8 ld_frag_glb(const u16* p) {
  u32x4 v = *(const u32x4*)p;
  return __builtin_bit_cast(bf16x8, v);
}

// ---------------------------------------------------------------------------
// Prep: convert W2a [256x256] f32 and W2b [256x64] f32 into bf16 fragments.
// Used as MFMA *A*-operands (W^T tiles):
//   wfA[((ntg*8 + ks)*64 + lane)*8 + q] = W2a[ks*32 + (lane>>4)*8 + q][ntg*16 + (lane&15)]
//   (= W2a^T[n][k] with n-row = lane&15, k = ks*32 + (lane>>4)*8 + q)
// ---------------------------------------------------------------------------
__global__ void prep_kernel(const float* __restrict__ W2a, const float* __restrict__ W2b,
                            u16* __restrict__ wfA, u16* __restrict__ wfB) {
  int t = blockIdx.x * 256 + threadIdx.x;
  if (t < 8192) {  // 16 ntiles * 8 ksteps * 64 lanes
    int lane = t & 63;
    int ks = (t >> 6) & 7;
    int ntg = t >> 9;  // 0..15
    int col = (ntg << 4) + (lane & 15);
    int kb = (ks << 5) + ((lane >> 4) << 3);
#pragma unroll
    for (int q = 0; q < 8; ++q)
      wfA[t * 8 + q] = f2bf(W2a[(kb + q) * 256 + col]);
  } else if (t < 10240) {  // 4 ntiles * 8 ksteps * 64 lanes
    int t2 = t - 8192;
    int lane = t2 & 63;
    int ks = (t2 >> 6) & 7;
    int ntg = t2 >> 9;  // 0..3
    int col = (ntg << 4) + (lane & 15);
    int kb = (ks << 5) + ((lane >> 4) << 3);
#pragma unroll
    for (int q = 0; q < 8; ++q)
      wfB[t2 * 8 + q] = f2bf(W2b[(kb + q) * 64 + col]);
  }
}

// ---------------------------------------------------------------------------
// Fused kernel. Blocks [0,8192): out2 path. Blocks [8192,10240): out1 path.
//
// out2: one block = (b, i, j-tile of 64). Fused MLP with bf16 MFMA,
// SWAPPED operands: mfma(W^T_frag /*A*/, X_frag /*B*/, acc) so the C/D
// fragment is contiguous along the weight-output dim (n / d):
//   acc[...][e]: col(j) = lane&15, row(n or d) = 4*(lane>>4)+e.
// => H-write packs 4 u16 -> ds_write_b64; out2 store is float4.
//
// Single 32 KB LDS buffer S: X during GEMM1, reused for H in GEMM2.
// XOR swizzle: byte ^= (row&7)<<4 (rows are 512B). 16B LDS writes/reads
// are bank-balanced under this swizzle (8 lanes per 4-bank granule).
//
// __launch_bounds__(256,2): R1-proven 88 VGPR, NO spill. (256,4)/(256,5)
// both forced spill (R2: 48 VGPR +900MB scratch; R3: 64 VGPR +188MB).
// Occupancy = VGPR-bound 4 blocks/CU = 50% (LDS allows 5).
// ---------------------------------------------------------------------------
__global__ __launch_bounds__(256, 2) void fused_kernel(
    const float* __restrict__ emb1, const float* __restrict__ emb2,
    const float* __restrict__ W1a, const float* __restrict__ b1a,
    const float* __restrict__ W1b, const float* __restrict__ b1b,
    const float* __restrict__ b2a, const float* __restrict__ b2b,
    const u16* __restrict__ wfA, const u16* __restrict__ wfB,
    float* __restrict__ out1, float* __restrict__ out2) {
  __shared__ __align__(16) u16 S[64 * 256];  // 32 KB

  int blk = blockIdx.x;
  int t = threadIdx.x;

  if (blk >= 8192) {
    // ---------------- out1 path ----------------
    int bi = blk - 8192;  // b*256 + i
    float* f = (float*)S;
    float* smax = f;        // [4][64]
    float* smin = f + 256;  // [4][64]
    float* cat1 = f + 512;  // [192]
    float* h    = f + 704;  // [128]

    int d = t & 63, q = t >> 6;
    const float* base = emb2 + (size_t)bi * 256 * 64;
    float vmax = -INFINITY, vmin = INFINITY;
    for (int j = q; j < 256; j += 4) {
      float v = base[j * 64 + d];
      vmax = fmaxf(vmax, v);
      vmin = fminf(vmin, v);
    }
    smax[q * 64 + d] = vmax;
    smin[q * 64 + d] = vmin;
    __syncthreads();
    if (t < 64) {
      float mx = fmaxf(fmaxf(smax[t], smax[64 + t]), fmaxf(smax[128 + t], smax[192 + t]));
      float mn = fminf(fminf(smin[t], smin[64 + t]), fminf(smin[128 + t], smin[192 + t]));
      cat1[t] = emb1[bi * 64 + t];
      cat1[64 + t] = mx;
      cat1[128 + t] = mn;
    }
    __syncthreads();
    if (t < 128) {
      float acc = b1a[t];
      for (int k = 0; k < 192; ++k) acc += cat1[k] * W1a[k * 128 + t];
      h[t] = fmaxf(acc, 0.f);
    }
    __syncthreads();
    if (t < 64) {
      float acc = b1b[t];
      for (int k = 0; k < 128; ++k) acc += h[k] * W1b[k * 64 + t];
      out1[bi * 64 + t] = acc;
    }
    return;
  }

  // ---------------- out2 path ----------------
  int b = blk >> 10;
  int i = (blk >> 2) & 255;
  int j0 = (blk & 3) << 6;
  int lane = t & 63;
  int w = t >> 6;
  int lr = lane & 15;  // row/col within 16-tile
  int lg = lane >> 4;  // k-group

  // ---- stage X: 64 rows x 256 feats -> bf16 LDS (swizzled), 16B writes ----
  {
    int r = t >> 2;
    int c16 = (t & 3) << 4;  // 16-float chunk within each 64-float segment
    const float* s0 = emb1 + ((b << 8) + j0 + r) * 64;
    const float* s1 = emb2 + ((((size_t)(b << 8) + j0 + r) << 8) + i) * 64;
    const float* s2 = emb1 + ((b << 8) + i) * 64;
    const float* s3 = emb2 + ((((size_t)(b << 8) + i) << 8) + (j0 + r)) * 64;
    const float* srcs[4] = {s0, s1, s2, s3};
#pragma unroll
    for (int seg = 0; seg < 4; ++seg) {
      const float* src = srcs[seg];
#pragma unroll
      for (int u = 0; u < 2; ++u) {
        int d = c16 + (u << 3);
        float4 v0 = *(const float4*)(src + d);
        float4 v1 = *(const float4*)(src + d + 4);
        u16x8 o = {f2bf(v0.x), f2bf(v0.y), f2bf(v0.z), f2bf(v0.w),
                   f2bf(v1.x), f2bf(v1.y), f2bf(v1.z), f2bf(v1.w)};
        int byteOff = (r * 512 + ((seg << 6) + d) * 2) ^ ((r & 7) << 4);
        *(u16x8*)((char*)S + byteOff) = o;
      }
    }
  }
  __syncthreads();

  // ---- GEMM1 (swapped): H^T = W2a^T @ X^T; wave w owns n in [w*64, w*64+64) ----
  f32x4 acc1[4][4];
#pragma unroll
  for (int m = 0; m < 4; ++m)
#pragma unroll
    for (int nt = 0; nt < 4; ++nt) acc1[m][nt] = (f32x4){0.f, 0.f, 0.f, 0.f};

#pragma unroll
  for (int ks = 0; ks < 8; ++ks) {
    int kByte = (ks << 6) + (lg << 4);  // (ks*32 + lg*8) bf16 -> bytes
    bf16x8 a[4];
#pragma unroll
    for (int m = 0; m < 4; ++m) {
      int r = (m << 4) + lr;
      int off = (r * 512 + kByte) ^ ((r & 7) << 4);
      a[m] = ld_frag_lds(S, off);
    }
    bf16x8 bw[4];
#pragma unroll
    for (int nt = 0; nt < 4; ++nt)
      bw[nt] = ld_frag_glb(wfA + (size_t)((((w << 2) + nt) * 8 + ks) * 64 + lane) * 8);
#pragma unroll
    for (int m = 0; m < 4; ++m)
#pragma unroll
      for (int nt = 0; nt < 4; ++nt)
        acc1[m][nt] = __builtin_amdgcn_mfma_f32_16x16x32_bf16(bw[nt], a[m], acc1[m][nt], 0, 0, 0);
  }

  __syncthreads();  // all waves done READING X before S is overwritten with H

  // ---- bias + relu -> S as H (bf16, row-major [j][n], swizzled) ----
  // acc1[m][nt][e]: j = m*16 + lr, n = w*64 + nt*16 + lg*4 + e  (contiguous e!)
#pragma unroll
  for (int nt = 0; nt < 4; ++nt) {
    float4 bias4 = *(const float4*)(b2a + (w << 6) + (nt << 4) + (lg << 2));
#pragma unroll
    for (int m = 0; m < 4; ++m) {
      int j = (m << 4) + lr;
      u16x4 o = {f2bf(fmaxf(acc1[m][nt][0] + bias4.x, 0.f)),
                 f2bf(fmaxf(acc1[m][nt][1] + bias4.y, 0.f)),
                 f2bf(fmaxf(acc1[m][nt][2] + bias4.z, 0.f)),
                 f2bf(fmaxf(acc1[m][nt][3] + bias4.w, 0.f))};
      int nByte = ((w << 6) + (nt << 4) + (lg << 2)) * 2;
      int off = (j * 512 + nByte) ^ ((j & 7) << 4);
      *(u16x4*)((char*)S + off) = o;
    }
  }
  __syncthreads();

  // ---- GEMM2 (swapped): O^T = W2b^T @ H^T; wave w owns d in [w*16, w*16+16) ----
  f32x4 acc2[4];
#pragma unroll
  for (int jt = 0; jt < 4; ++jt) acc2[jt] = (f32x4){0.f, 0.f, 0.f, 0.f};

#pragma unroll
  for (int ks = 0; ks < 8; ++ks) {
    int kByte = (ks << 6) + (lg << 4);
    bf16x8 bwB = ld_frag_glb(wfB + (size_t)(((w << 3) + ks) * 64 + lane) * 8);
#pragma unroll
    for (int jt = 0; jt < 4; ++jt) {
      int j = (jt << 4) + lr;
      int off = (j * 512 + kByte) ^ ((j & 7) << 4);
      bf16x8 h = ld_frag_lds(S, off);
      acc2[jt] = __builtin_amdgcn_mfma_f32_16x16x32_bf16(bwB, h, acc2[jt], 0, 0, 0);
    }
  }

  // ---- store out2 tile (f32, float4 along d) ----
  // acc2[jt][e]: j = jt*16 + lr, d = w*16 + lg*4 + e
  float4 bias2 = *(const float4*)(b2b + (w << 4) + (lg << 2));
  float* obase = out2 + ((((size_t)(b << 8) + i) << 8) + j0) * 64 + (w << 4) + (lg << 2);
#pragma unroll
  for (int jt = 0; jt < 4; ++jt) {
    float4 v = {acc2[jt][0] + bias2.x, acc2[jt][1] + bias2.y,
                acc2[jt][2] + bias2.z, acc2[jt][3] + bias2.w};
    *(float4*)(obase + (size_t)((jt << 4) + lr) * 64) = v;
  }
}

extern "C" void kernel_launch(void* const* d_in, const int* in_sizes, int n_in,
                              void* d_out, int out_size, void* d_ws, size_t ws_size,
                              hipStream_t stream) {
  const float* emb1 = (const float*)d_in[0];
  const float* emb2 = (const float*)d_in[1];
  const float* W1a  = (const float*)d_in[2];
  const float* b1a  = (const float*)d_in[3];
  const float* W1b  = (const float*)d_in[4];
  const float* b1b  = (const float*)d_in[5];
  const float* W2a  = (const float*)d_in[6];
  const float* b2a  = (const float*)d_in[7];
  const float* W2b  = (const float*)d_in[8];
  const float* b2b  = (const float*)d_in[9];

  float* out = (float*)d_out;
  u16* wfA = (u16*)d_ws;               // 16*8*64*8 = 65536 bf16 = 128 KB
  u16* wfB = wfA + 16 * 8 * 64 * 8;    //  4*8*64*8 = 16384 bf16 =  32 KB

  prep_kernel<<<40, 256, 0, stream>>>(W2a, W2b, wfA, wfB);
  fused_kernel<<<10240, 256, 0, stream>>>(emb1, emb2, W1a, b1a, W1b, b1b,
                                          b2a, b2b, wfA, wfB,
                                          out, out + 8 * 256 * 64);
}